// Round 1
// baseline (150.419 us; speedup 1.0000x reference)
//
#include <hip/hip_runtime.h>
#include <hip/hip_bf16.h>
#include <math.h>

#define D 384
#define EPS 1e-8f

#define RPB 256            // rows per block (4 waves x 64)
#define CPS 512            // cols per split
#define POS_W 128          // cols per position (fold granularity)
#define NPOS 4             // 512/128
#define NKB 12             // 384/32 k-steps

typedef __bf16  bf16x8  __attribute__((ext_vector_type(8)));
typedef float   floatx4 __attribute__((ext_vector_type(4)));

// ---------------- kernel 1: rnorm + normalized bf16 cast ----------------
__global__ __launch_bounds__(256) void prep_kernel(const float* __restrict__ in,
                                                   float* __restrict__ rnorm,
                                                   __hip_bfloat16* __restrict__ xb, int N) {
    int row = blockIdx.x * 4 + (threadIdx.x >> 6);   // one wave per row
    if (row >= N) return;
    int lane = threadIdx.x & 63;
    const float* p = in + (size_t)row * D;
    float v[6];
    float s = 0.f;
#pragma unroll
    for (int c = 0; c < 6; ++c) { v[c] = p[lane + 64 * c]; s += v[c] * v[c]; }
#pragma unroll
    for (int off = 32; off >= 1; off >>= 1) s += __shfl_xor(s, off, 64);
    float rn = 1.0f / fmaxf(sqrtf(s), EPS);
    if (lane == 0) rnorm[row] = rn;
    __hip_bfloat16* q = xb + (size_t)row * D;
#pragma unroll
    for (int c = 0; c < 6; ++c) q[lane + 64 * c] = __float2bfloat16(v[c] * rn);
}

// ---------------- kernel 2: row-ownership MFMA scan, 2-phase pipelined ----------------
// Block owns 256 rows, scans 512 cols (4 positions of 128). B double-buffers
// through 2x8 KB LDS (global_load_lds); the NEXT k-step's stage is issued
// BEFORE the current k-step's ds_read+MFMA region, and there is ONE barrier
// per k-step (was 2). The compiler's pre-barrier vmcnt(0) drain thus lands
// after ~620 cyc of MFMA instead of before it -> staging latency hidden
// (T3-minimum 2-phase pattern). A fragments load straight global->VGPR
// (issued FIRST so their consume-wait is vmcnt(2), leaving glds in flight).
__global__ __launch_bounds__(256, 2) void maxdot_rows(const __hip_bfloat16* __restrict__ xb,
                                                      unsigned long long* __restrict__ best) {
    __shared__ char Bs[2][POS_W * 64];               // 2 x 8 KB: 128 cols x 64 B (32 k)

    const int t    = threadIdx.x;
    const int lane = t & 63;
    const int wv   = t >> 6;
    const int quad = lane >> 4, l16 = lane & 15;
    const int rb   = blockIdx.x >> 4;                // 32 row-blocks
    const int cs   = blockIdx.x & 15;                // 16 col-splits
    const int row0b = rb * RPB;
    const int col0s = cs * CPS;
    const int wrow0 = row0b + wv * 64;

    floatx4 acc[4][8];
#pragma unroll
    for (int mi = 0; mi < 4; ++mi)
#pragma unroll
        for (int ni = 0; ni < 8; ++ni) acc[mi][ni] = (floatx4){0.f, 0.f, 0.f, 0.f};

    float rv[16];
    int   ri[16];
#pragma unroll
    for (int i = 0; i < 16; ++i) { rv[i] = -3.0f; ri[i] = 0; }

    // B staging indices: p = t (+256): col = p>>2, 16-B granule = p&3
    const int sc0 = t >> 2,       sg0 = t & 3;
    const int sc1 = (t + 256) >> 2, sg1 = (t + 256) & 3;

    // prologue: stage (pos=0, kb=0) into buf 0
    {
        const char* g0 = (const char*)(xb + (size_t)(col0s + sc0) * D) + sg0 * 16;
        const char* g1 = (const char*)(xb + (size_t)(col0s + sc1) * D) + sg1 * 16;
        __builtin_amdgcn_global_load_lds((const __attribute__((address_space(1))) void*)g0,
                                         (__attribute__((address_space(3))) void*)(Bs[0] + t * 16), 16, 0, 0);
        __builtin_amdgcn_global_load_lds((const __attribute__((address_space(1))) void*)g1,
                                         (__attribute__((address_space(3))) void*)(Bs[0] + (t + 256) * 16), 16, 0, 0);
    }
    __syncthreads();

    int cur = 0;
    for (int pos = 0; pos < NPOS; ++pos) {
        const int colbase = col0s + pos * POS_W;

        for (int kb = 0; kb < NKB; ++kb) {
            // A fragments straight from global, issued FIRST (consume-wait = vmcnt(2))
            bf16x8 af[4];
#pragma unroll
            for (int mi = 0; mi < 4; ++mi)
                af[mi] = *(const bf16x8*)(xb + (size_t)(wrow0 + mi * 16 + l16) * D + kb * 32 + quad * 8);

            // stage NEXT k-step's B tile into the other buffer (stays in flight
            // across the whole MFMA region; drained only at the barrier below)
            int nkb = kb + 1, npos = pos;
            if (nkb == NKB) { nkb = 0; ++npos; }
            if (npos < NPOS) {
                const int ncb = col0s + npos * POS_W;
                const char* g0 = (const char*)(xb + (size_t)(ncb + sc0) * D + nkb * 32) + sg0 * 16;
                const char* g1 = (const char*)(xb + (size_t)(ncb + sc1) * D + nkb * 32) + sg1 * 16;
                char* dst = Bs[cur ^ 1];
                __builtin_amdgcn_global_load_lds((const __attribute__((address_space(1))) void*)g0,
                                                 (__attribute__((address_space(3))) void*)(dst + t * 16), 16, 0, 0);
                __builtin_amdgcn_global_load_lds((const __attribute__((address_space(1))) void*)g1,
                                                 (__attribute__((address_space(3))) void*)(dst + (t + 256) * 16), 16, 0, 0);
            }

            // compute current tile from buf[cur]
            const char* src = Bs[cur];
            bf16x8 bfr[8];
#pragma unroll
            for (int ni = 0; ni < 8; ++ni)
                bfr[ni] = *(const bf16x8*)(src + (ni * 16 + l16) * 64 + quad * 16);
#pragma unroll
            for (int mi = 0; mi < 4; ++mi)
#pragma unroll
                for (int ni = 0; ni < 8; ++ni)
                    acc[mi][ni] = __builtin_amdgcn_mfma_f32_16x16x32_bf16(af[mi], bfr[ni], acc[mi][ni], 0, 0, 0);

            __syncthreads();                         // one barrier/k-step: drains next-tile glds,
            cur ^= 1;                                // and prior ds_reads of the buffer we stage next
        }

        // ---- fold position into running (val, col); then zero acc ----
        const bool dg = (colbase < row0b + RPB) && (row0b < colbase + POS_W);
#pragma unroll
        for (int mi = 0; mi < 4; ++mi)
#pragma unroll
            for (int reg = 0; reg < 4; ++reg) {
                const int r = wrow0 + mi * 16 + quad * 4 + reg;
                float d[8];
#pragma unroll
                for (int ni = 0; ni < 8; ++ni) d[ni] = acc[mi][ni][reg];
                if (dg) {
#pragma unroll
                    for (int ni = 0; ni < 8; ++ni)
                        if (colbase + ni * 16 + l16 == r) d[ni] = -2.0f;
                }
                float m = d[0]; int ci = 0;
#pragma unroll
                for (int ni = 1; ni < 8; ++ni) {     // ties -> lower ni (lower col)
                    bool gt = d[ni] > m;
                    m  = gt ? d[ni] : m;
                    ci = gt ? ni : ci;
                }
                const int slot = mi * 4 + reg;
                bool upd = m > rv[slot];             // ties -> earlier position (lower col)
                rv[slot] = upd ? m : rv[slot];
                ri[slot] = upd ? (colbase + ci * 16 + l16) : ri[slot];
#pragma unroll
                for (int ni = 0; ni < 8; ++ni) acc[mi][ni][reg] = 0.f;
            }
    }

    // ---- final cross-lane reduce over the 16 col-lanes, one atomic per row ----
#pragma unroll
    for (int slot = 0; slot < 16; ++slot) {
        float v = rv[slot]; int ci = ri[slot];
#pragma unroll
        for (int m = 1; m < 16; m <<= 1) {
            float ov = __shfl_xor(v, m, 64);
            int   oi = __shfl_xor(ci, m, 64);
            bool take = (ov > v) || (ov == v && oi < ci);
            v  = take ? ov : v;
            ci = take ? oi : ci;
        }
        if (l16 == 0) {
            const int r = wrow0 + (slot >> 2) * 16 + quad * 4 + (slot & 3);
            unsigned u = __float_as_uint(v);
            u = (u & 0x80000000u) ? ~u : (u | 0x80000000u);
            unsigned long long key = ((unsigned long long)u << 32) | (unsigned)(~ci);
            atomicMax(best + r, key);
        }
    }
}

// ---------------- kernel 3: exact fp32 distance + loss ----------------
__global__ __launch_bounds__(256) void loss_kernel(const float* __restrict__ in,
                                                   const float* __restrict__ rnorm,
                                                   const unsigned long long* __restrict__ best,
                                                   float* __restrict__ out, int N) {
    __shared__ float part[4];
    const int wave = threadIdx.x >> 6, lane = threadIdx.x & 63;
    const int gw = blockIdx.x * 4 + wave;            // 1024 waves total
    float local = 0.f;
    for (int row = gw; row < N; row += 1024) {
        unsigned long long key = best[row];
        int j = (int)(~(unsigned)(key & 0xffffffffull));
        float rni = rnorm[row], rnj = rnorm[j];
        const float* pi = in + (size_t)row * D;
        const float* pj = in + (size_t)j * D;
        float s = 0.f;
#pragma unroll
        for (int c = 0; c < 6; ++c) {
            float xi = pi[lane + 64 * c] * rni;
            float xj = pj[lane + 64 * c] * rnj;
            float dvv = xi - xj + EPS;               // ||x - nn_x + eps||
            s += dvv * dvv;
        }
#pragma unroll
        for (int off = 32; off > 0; off >>= 1) s += __shfl_down(s, off, 64);
        if (lane == 0) local += -logf(sqrtf(s) + EPS);
    }
    if (lane == 0) part[wave] = local;
    __syncthreads();
    if (threadIdx.x == 0)
        atomicAdd(out, (part[0] + part[1] + part[2] + part[3]) / (float)N);
}

extern "C" void kernel_launch(void* const* d_in, const int* in_sizes, int n_in,
                              void* d_out, int out_size, void* d_ws, size_t ws_size,
                              hipStream_t stream) {
    const float* in = (const float*)d_in[0];
    float* out = (float*)d_out;
    const int N = in_sizes[0] / D;                   // 8192

    // workspace layout: rnorm (N f32) | best (N u64) | xb (N*D bf16)
    char* ws = (char*)d_ws;
    float* rnorm = (float*)ws;
    unsigned long long* best = (unsigned long long*)(ws + 64 * 1024);
    __hip_bfloat16* xb = (__hip_bfloat16*)(ws + 192 * 1024);

    (void)hipMemsetAsync(best, 0, (size_t)N * 8, stream);  // ws re-poisoned each call
    (void)hipMemsetAsync(out, 0, sizeof(float), stream);

    prep_kernel<<<N / 4, 256, 0, stream>>>(in, rnorm, xb, N);
    maxdot_rows<<<512, 256, 0, stream>>>(xb, best);        // 32 row-blocks x 16 col-splits
    loss_kernel<<<256, 256, 0, stream>>>(in, rnorm, best, out, N);
}

// Round 2
// 144.077 us; speedup vs baseline: 1.0440x; 1.0440x over previous
//
#include <hip/hip_runtime.h>
#include <hip/hip_bf16.h>
#include <math.h>

#define D 384
#define EPS 1e-8f

#define RPB 256            // rows per block (4 waves x 64)
#define CPS 512            // cols per split
#define POS_W 128          // cols per position (fold granularity)
#define NPOS 4             // 512/128
#define NKB 12             // 384/32 k-steps
#define NT  48             // NPOS * NKB tiles per block

typedef __bf16  bf16x8  __attribute__((ext_vector_type(8)));
typedef float   floatx4 __attribute__((ext_vector_type(4)));

// ---------------- kernel 1: rnorm + normalized bf16 cast ----------------
__global__ __launch_bounds__(256) void prep_kernel(const float* __restrict__ in,
                                                   float* __restrict__ rnorm,
                                                   __hip_bfloat16* __restrict__ xb, int N) {
    int row = blockIdx.x * 4 + (threadIdx.x >> 6);   // one wave per row
    if (row >= N) return;
    int lane = threadIdx.x & 63;
    const float* p = in + (size_t)row * D;
    float v[6];
    float s = 0.f;
#pragma unroll
    for (int c = 0; c < 6; ++c) { v[c] = p[lane + 64 * c]; s += v[c] * v[c]; }
#pragma unroll
    for (int off = 32; off >= 1; off >>= 1) s += __shfl_xor(s, off, 64);
    float rn = 1.0f / fmaxf(sqrtf(s), EPS);
    if (lane == 0) rnorm[row] = rn;
    __hip_bfloat16* q = xb + (size_t)row * D;
#pragma unroll
    for (int c = 0; c < 6; ++c) q[lane + 64 * c] = __float2bfloat16(v[c] * rn);
}

// ---------------- kernel 2: row-ownership MFMA scan, counted-vmcnt pipeline ----------------
// 2 waves/SIMD (register-capped: 128 acc + ~128 arch VGPR on the unified file),
// so latency hiding must be in-wave. 4-buffer LDS rotation, stage tile k+3
// during k-step k; raw s_barrier + asm "s_waitcnt vmcnt(4)" instead of
// __syncthreads so tiles k+1/k+2 stay in flight ACROSS the barrier (T4).
// Correctness: each wave's vmcnt(4) before the barrier guarantees its own
// tile-k glds completed (they always have >=4 newer glds behind them except
// the 2-tile tail, peeled to vmcnt(2)/vmcnt(0)); buffer overwrite (k+3 vs
// reads at k-1) is ordered by the barrier because every wave's ds_reads are
// register-consumed (lgkm-waited) before its MFMAs issue, hence before it
// arrives at the barrier. A frags load global->VGPR right after the barrier,
// BEFORE the glds issue, so their consume-wait leaves the newest glds in
// flight; their L2 latency hides under the 8 ds_read_b128.
__global__ __launch_bounds__(256, 2) void maxdot_rows(const __hip_bfloat16* __restrict__ xb,
                                                      unsigned long long* __restrict__ best) {
    __shared__ char Bs[4][POS_W * 64];               // 4 x 8 KB rotation

    const int t    = threadIdx.x;
    const int lane = t & 63;
    const int wv   = t >> 6;
    const int quad = lane >> 4, l16 = lane & 15;
    const int rb   = blockIdx.x >> 4;                // 32 row-blocks
    const int cs   = blockIdx.x & 15;                // 16 col-splits
    const int row0b = rb * RPB;
    const int col0s = cs * CPS;
    const int wrow0 = row0b + wv * 64;

    floatx4 acc[4][8];
#pragma unroll
    for (int mi = 0; mi < 4; ++mi)
#pragma unroll
        for (int ni = 0; ni < 8; ++ni) acc[mi][ni] = (floatx4){0.f, 0.f, 0.f, 0.f};

    float rv[16];
    int   ri[16];
#pragma unroll
    for (int i = 0; i < 16; ++i) { rv[i] = -3.0f; ri[i] = 0; }

    // B staging indices: p = t (+256): col = p>>2, 16-B granule = p&3
    const int sc0 = t >> 2,         sg0 = t & 3;
    const int sc1 = (t + 256) >> 2, sg1 = (t + 256) & 3;

#define STAGE(TT) do {                                                                 \
        const int p_  = (TT) / NKB, kb_ = (TT) - p_ * NKB;                             \
        const int cb_ = col0s + p_ * POS_W;                                            \
        const char* g0_ = (const char*)(xb + (size_t)(cb_ + sc0) * D + kb_ * 32) + sg0 * 16; \
        const char* g1_ = (const char*)(xb + (size_t)(cb_ + sc1) * D + kb_ * 32) + sg1 * 16; \
        char* d_ = Bs[(TT) & 3];                                                       \
        __builtin_amdgcn_global_load_lds((const __attribute__((address_space(1))) void*)g0_, \
                                         (__attribute__((address_space(3))) void*)(d_ + t * 16), 16, 0, 0); \
        __builtin_amdgcn_global_load_lds((const __attribute__((address_space(1))) void*)g1_, \
                                         (__attribute__((address_space(3))) void*)(d_ + (t + 256) * 16), 16, 0, 0); \
    } while (0)

    // prologue: 3 tiles in flight
    STAGE(0); STAGE(1); STAGE(2);

    for (int tt = 0; tt < NT; ++tt) {
        const int pos = tt / NKB, kb = tt - pos * NKB;
        const int colbase = col0s + pos * POS_W;

        // tile tt's glds done; tiles tt+1, tt+2 stay in flight across the barrier
        if (tt < NT - 2)       asm volatile("s_waitcnt vmcnt(4)" ::: "memory");
        else if (tt == NT - 2) asm volatile("s_waitcnt vmcnt(2)" ::: "memory");
        else                   asm volatile("s_waitcnt vmcnt(0)" ::: "memory");
        __builtin_amdgcn_s_barrier();
        __builtin_amdgcn_sched_barrier(0);

        // A fragments straight from global, issued FIRST (their consume-wait
        // then leaves the newest glds outstanding)
        bf16x8 af[4];
#pragma unroll
        for (int mi = 0; mi < 4; ++mi)
            af[mi] = *(const bf16x8*)(xb + (size_t)(wrow0 + mi * 16 + l16) * D + kb * 32 + quad * 8);

        // stage tile tt+3 into the buffer last read at tt-1
        if (tt + 3 < NT) STAGE(tt + 3);

        // compute current tile from buf[tt&3]
        const char* src = Bs[tt & 3];
        bf16x8 bfr[8];
#pragma unroll
        for (int ni = 0; ni < 8; ++ni)
            bfr[ni] = *(const bf16x8*)(src + (ni * 16 + l16) * 64 + quad * 16);
#pragma unroll
        for (int mi = 0; mi < 4; ++mi)
#pragma unroll
            for (int ni = 0; ni < 8; ++ni)
                acc[mi][ni] = __builtin_amdgcn_mfma_f32_16x16x32_bf16(af[mi], bfr[ni], acc[mi][ni], 0, 0, 0);

        // ---- end of a position: fold into running (val, col); zero acc ----
        if (kb == NKB - 1) {
            const bool dg = (colbase < row0b + RPB) && (row0b < colbase + POS_W);
#pragma unroll
            for (int mi = 0; mi < 4; ++mi)
#pragma unroll
                for (int reg = 0; reg < 4; ++reg) {
                    const int r = wrow0 + mi * 16 + quad * 4 + reg;
                    float d[8];
#pragma unroll
                    for (int ni = 0; ni < 8; ++ni) d[ni] = acc[mi][ni][reg];
                    if (dg) {
#pragma unroll
                        for (int ni = 0; ni < 8; ++ni)
                            if (colbase + ni * 16 + l16 == r) d[ni] = -2.0f;
                    }
                    float m = d[0]; int ci = 0;
#pragma unroll
                    for (int ni = 1; ni < 8; ++ni) {     // ties -> lower ni (lower col)
                        bool gt = d[ni] > m;
                        m  = gt ? d[ni] : m;
                        ci = gt ? ni : ci;
                    }
                    const int slot = mi * 4 + reg;
                    bool upd = m > rv[slot];             // ties -> earlier position (lower col)
                    rv[slot] = upd ? m : rv[slot];
                    ri[slot] = upd ? (colbase + ci * 16 + l16) : ri[slot];
#pragma unroll
                    for (int ni = 0; ni < 8; ++ni) acc[mi][ni][reg] = 0.f;
                }
        }
    }
#undef STAGE

    // ---- final cross-lane reduce over the 16 col-lanes, one atomic per row ----
#pragma unroll
    for (int slot = 0; slot < 16; ++slot) {
        float v = rv[slot]; int ci = ri[slot];
#pragma unroll
        for (int m = 1; m < 16; m <<= 1) {
            float ov = __shfl_xor(v, m, 64);
            int   oi = __shfl_xor(ci, m, 64);
            bool take = (ov > v) || (ov == v && oi < ci);
            v  = take ? ov : v;
            ci = take ? oi : ci;
        }
        if (l16 == 0) {
            const int r = wrow0 + (slot >> 2) * 16 + quad * 4 + (slot & 3);
            unsigned u = __float_as_uint(v);
            u = (u & 0x80000000u) ? ~u : (u | 0x80000000u);
            unsigned long long key = ((unsigned long long)u << 32) | (unsigned)(~ci);
            atomicMax(best + r, key);
        }
    }
}

// ---------------- kernel 3: exact fp32 distance + loss ----------------
__global__ __launch_bounds__(256) void loss_kernel(const float* __restrict__ in,
                                                   const float* __restrict__ rnorm,
                                                   const unsigned long long* __restrict__ best,
                                                   float* __restrict__ out, int N) {
    __shared__ float part[4];
    const int wave = threadIdx.x >> 6, lane = threadIdx.x & 63;
    const int gw = blockIdx.x * 4 + wave;            // 1024 waves total
    float local = 0.f;
    for (int row = gw; row < N; row += 1024) {
        unsigned long long key = best[row];
        int j = (int)(~(unsigned)(key & 0xffffffffull));
        float rni = rnorm[row], rnj = rnorm[j];
        const float* pi = in + (size_t)row * D;
        const float* pj = in + (size_t)j * D;
        float s = 0.f;
#pragma unroll
        for (int c = 0; c < 6; ++c) {
            float xi = pi[lane + 64 * c] * rni;
            float xj = pj[lane + 64 * c] * rnj;
            float dvv = xi - xj + EPS;               // ||x - nn_x + eps||
            s += dvv * dvv;
        }
#pragma unroll
        for (int off = 32; off > 0; off >>= 1) s += __shfl_down(s, off, 64);
        if (lane == 0) local += -logf(sqrtf(s) + EPS);
    }
    if (lane == 0) part[wave] = local;
    __syncthreads();
    if (threadIdx.x == 0)
        atomicAdd(out, (part[0] + part[1] + part[2] + part[3]) / (float)N);
}

extern "C" void kernel_launch(void* const* d_in, const int* in_sizes, int n_in,
                              void* d_out, int out_size, void* d_ws, size_t ws_size,
                              hipStream_t stream) {
    const float* in = (const float*)d_in[0];
    float* out = (float*)d_out;
    const int N = in_sizes[0] / D;                   // 8192

    // workspace layout: rnorm (N f32) | best (N u64) | xb (N*D bf16)
    char* ws = (char*)d_ws;
    float* rnorm = (float*)ws;
    unsigned long long* best = (unsigned long long*)(ws + 64 * 1024);
    __hip_bfloat16* xb = (__hip_bfloat16*)(ws + 192 * 1024);

    (void)hipMemsetAsync(best, 0, (size_t)N * 8, stream);  // ws re-poisoned each call
    (void)hipMemsetAsync(out, 0, sizeof(float), stream);

    prep_kernel<<<N / 4, 256, 0, stream>>>(in, rnorm, xb, N);
    maxdot_rows<<<512, 256, 0, stream>>>(xb, best);        // 32 row-blocks x 16 col-splits
    loss_kernel<<<256, 256, 0, stream>>>(in, rnorm, best, out, N);
}

// Round 4
// 131.376 us; speedup vs baseline: 1.1450x; 1.0967x over previous
//
#include <hip/hip_runtime.h>
#include <hip/hip_bf16.h>
#include <math.h>

#define D 384
#define EPS 1e-8f

#define RPB 256            // rows per block (4 waves x 64)
#define CPS 512            // cols per split
#define POS_W 128          // cols per position (fold granularity)
#define NPOS 4             // 512/128
#define NKB 12             // 384/32 k-steps
#define NT  48             // NPOS * NKB tiles per block
#define STG 24576          // stage bytes: 8 KB B (128 cols x 64 B) + 16 KB A (256 rows x 64 B)

typedef __bf16  bf16x8  __attribute__((ext_vector_type(8)));
typedef float   floatx4 __attribute__((ext_vector_type(4)));

// ---------------- kernel 1: rnorm + normalized bf16 cast + ws init ----------------
__global__ __launch_bounds__(256) void prep_kernel(const float* __restrict__ in,
                                                   float* __restrict__ rnorm,
                                                   __hip_bfloat16* __restrict__ xb,
                                                   unsigned long long* __restrict__ best,
                                                   float* __restrict__ out, int N) {
    if (blockIdx.x == 0 && threadIdx.x == 0) *out = 0.f;   // replaces memset node
    int row = blockIdx.x * 4 + (threadIdx.x >> 6);   // one wave per row
    if (row >= N) return;
    int lane = threadIdx.x & 63;
    const float* p = in + (size_t)row * D;
    float v[6];
    float s = 0.f;
#pragma unroll
    for (int c = 0; c < 6; ++c) { v[c] = p[lane + 64 * c]; s += v[c] * v[c]; }
#pragma unroll
    for (int off = 32; off >= 1; off >>= 1) s += __shfl_xor(s, off, 64);
    float rn = 1.0f / fmaxf(sqrtf(s), EPS);
    if (lane == 0) { rnorm[row] = rn; best[row] = 0ull; }  // replaces memset node
    __hip_bfloat16* q = xb + (size_t)row * D;
#pragma unroll
    for (int c = 0; c < 6; ++c) q[lane + 64 * c] = __float2bfloat16(v[c] * rn);
}

// ---------------- kernel 2: row-ownership MFMA scan, A+B both LDS-staged ----------------
// R2 counters: 2 waves/SIMD (register-capped), MFMA 33% busy, nothing saturated
// -> the per-k-step A-fragment GLOBAL loads (~200-400 cyc L2) sat in the MFMA
// dep chain every iteration. Fix: stage A through LDS with the same counted-
// vmcnt pipeline. Stage = 24 KB (8 KB B + 16 KB A) = 96 B/thread = SIX glds
// per thread (R3's bug: only 3 -> half the A tile was garbage). 3-buffer
// rotation (72 KB/block, 2 blocks/CU = 144/160 KB), staged 2 tiles ahead,
// vmcnt(6) leaves exactly the next stage in flight across the barrier.
// LDS layout linear 16-B slots: B slot = col*4+granule (8 KB), A slot =
// row*4+granule (16 KB at +8192). Reader byte = idx*64 + quad*16 (uniform
// 8-lanes/slot bank spread == the conflict-free b128 floor; swizzle provably
// changes nothing here, so none used).
__global__ __launch_bounds__(256, 2) void maxdot_rows(const __hip_bfloat16* __restrict__ xb,
                                                      unsigned long long* __restrict__ best) {
    __shared__ char Bs[3][STG];

    const int t    = threadIdx.x;
    const int lane = t & 63;
    const int wv   = t >> 6;
    const int quad = lane >> 4, l16 = lane & 15;
    const int rb   = blockIdx.x >> 4;                // 32 row-blocks
    const int cs   = blockIdx.x & 15;                // 16 col-splits
    const int row0b = rb * RPB;
    const int col0s = cs * CPS;
    const int wrow0 = row0b + wv * 64;

    floatx4 acc[4][8];
#pragma unroll
    for (int mi = 0; mi < 4; ++mi)
#pragma unroll
        for (int ni = 0; ni < 8; ++ni) acc[mi][ni] = (floatx4){0.f, 0.f, 0.f, 0.f};

    float rv[16];
    int   ri[16];
#pragma unroll
    for (int i = 0; i < 16; ++i) { rv[i] = -3.0f; ri[i] = 0; }

    // staging: thread t owns granule sg = t&3 of B-cols {sc, sc+64} and
    // A-rows {sc, sc+64, sc+128, sc+192}, sc = t>>2. 6 x 16 B = 96 B/thread.
    const int sc = t >> 2;
    const int sg = t & 3;

#define GLDS(SRC, DST) __builtin_amdgcn_global_load_lds(                               \
        (const __attribute__((address_space(1))) void*)(SRC),                          \
        (__attribute__((address_space(3))) void*)(DST), 16, 0, 0)

#define STAGE(TT, BUF) do {                                                            \
        const int p_  = (TT) / NKB, kb_ = (TT) - p_ * NKB;                             \
        const int cb_ = col0s + p_ * POS_W;                                            \
        const size_t ko_ = (size_t)kb_ * 64 + sg * 16;                                 \
        const char* xbb_ = (const char*)xb;                                            \
        GLDS(xbb_ + (size_t)(cb_ + sc)        * 768 + ko_, (BUF) +         t * 16);    \
        GLDS(xbb_ + (size_t)(cb_ + 64 + sc)   * 768 + ko_, (BUF) +  4096 + t * 16);    \
        GLDS(xbb_ + (size_t)(row0b + sc)      * 768 + ko_, (BUF) +  8192 + t * 16);    \
        GLDS(xbb_ + (size_t)(row0b + 64 + sc) * 768 + ko_, (BUF) + 12288 + t * 16);    \
        GLDS(xbb_ + (size_t)(row0b + 128 + sc)* 768 + ko_, (BUF) + 16384 + t * 16);    \
        GLDS(xbb_ + (size_t)(row0b + 192 + sc)* 768 + ko_, (BUF) + 20480 + t * 16);    \
    } while (0)

    // prologue: 2 stages (12 glds) in flight
    STAGE(0, Bs[0]);
    STAGE(1, Bs[1]);

    char* b0 = Bs[0];                                // read this iter
    char* b1 = Bs[1];                                // read next iter
    char* b2 = Bs[2];                                // stage target this iter

    const int lofs = l16 * 64 + quad * 16;           // reader byte within a 64-B row

    for (int tt = 0; tt < NT; ++tt) {
        const int pos = tt / NKB, kb = tt - pos * NKB;
        const int colbase = col0s + pos * POS_W;

        // stage(tt) complete; stage(tt+1) (6 glds) stays in flight across barrier
        if (tt < NT - 1) asm volatile("s_waitcnt vmcnt(6)" ::: "memory");
        else             asm volatile("s_waitcnt vmcnt(0)" ::: "memory");
        __builtin_amdgcn_s_barrier();
        __builtin_amdgcn_sched_barrier(0);

        // stage tile tt+2 into the buffer all waves finished reading at tt-1
        // (ordered by the barrier above: ds_reads are lgkm-consumed pre-MFMA,
        // hence before each wave arrived)
        if (tt + 2 < NT) STAGE(tt + 2, b2);

        // A and B fragments from LDS (prefetched ~2 k-steps ago)
        const char* Ab = b0 + 8192 + wv * 4096;      // this wave's 64 rows
        bf16x8 af[4];
#pragma unroll
        for (int mi = 0; mi < 4; ++mi)
            af[mi] = *(const bf16x8*)(Ab + mi * 1024 + lofs);
        bf16x8 bfr[8];
#pragma unroll
        for (int ni = 0; ni < 8; ++ni)
            bfr[ni] = *(const bf16x8*)(b0 + ni * 1024 + lofs);
#pragma unroll
        for (int mi = 0; mi < 4; ++mi)
#pragma unroll
            for (int ni = 0; ni < 8; ++ni)
                acc[mi][ni] = __builtin_amdgcn_mfma_f32_16x16x32_bf16(af[mi], bfr[ni], acc[mi][ni], 0, 0, 0);

        // ---- end of a position: fold into running (val, col); zero acc ----
        if (kb == NKB - 1) {
            const bool dg = (colbase < row0b + RPB) && (row0b < colbase + POS_W);
#pragma unroll
            for (int mi = 0; mi < 4; ++mi)
#pragma unroll
                for (int reg = 0; reg < 4; ++reg) {
                    const int r = wrow0 + mi * 16 + quad * 4 + reg;
                    float d[8];
#pragma unroll
                    for (int ni = 0; ni < 8; ++ni) d[ni] = acc[mi][ni][reg];
                    if (dg) {
#pragma unroll
                        for (int ni = 0; ni < 8; ++ni)
                            if (colbase + ni * 16 + l16 == r) d[ni] = -2.0f;
                    }
                    float m = d[0]; int ci = 0;
#pragma unroll
                    for (int ni = 1; ni < 8; ++ni) {     // ties -> lower ni (lower col)
                        bool gt = d[ni] > m;
                        m  = gt ? d[ni] : m;
                        ci = gt ? ni : ci;
                    }
                    const int slot = mi * 4 + reg;
                    bool upd = m > rv[slot];             // ties -> earlier position (lower col)
                    rv[slot] = upd ? m : rv[slot];
                    ri[slot] = upd ? (colbase + ci * 16 + l16) : ri[slot];
#pragma unroll
                    for (int ni = 0; ni < 8; ++ni) acc[mi][ni][reg] = 0.f;
                }
        }

        // rotate buffers
        char* tmp = b0; b0 = b1; b1 = b2; b2 = tmp;
    }
#undef STAGE
#undef GLDS

    // ---- final cross-lane reduce over the 16 col-lanes, one atomic per row ----
#pragma unroll
    for (int slot = 0; slot < 16; ++slot) {
        float v = rv[slot]; int ci = ri[slot];
#pragma unroll
        for (int m = 1; m < 16; m <<= 1) {
            float ov = __shfl_xor(v, m, 64);
            int   oi = __shfl_xor(ci, m, 64);
            bool take = (ov > v) || (ov == v && oi < ci);
            v  = take ? ov : v;
            ci = take ? oi : ci;
        }
        if (l16 == 0) {
            const int r = wrow0 + (slot >> 2) * 16 + quad * 4 + (slot & 3);
            unsigned u = __float_as_uint(v);
            u = (u & 0x80000000u) ? ~u : (u | 0x80000000u);
            unsigned long long key = ((unsigned long long)u << 32) | (unsigned)(~ci);
            atomicMax(best + r, key);
        }
    }
}

// ---------------- kernel 3: exact fp32 distance + loss ----------------
__global__ __launch_bounds__(256) void loss_kernel(const float* __restrict__ in,
                                                   const float* __restrict__ rnorm,
                                                   const unsigned long long* __restrict__ best,
                                                   float* __restrict__ out, int N) {
    __shared__ float part[4];
    const int wave = threadIdx.x >> 6, lane = threadIdx.x & 63;
    const int gw = blockIdx.x * 4 + wave;            // 1024 waves total
    float local = 0.f;
    for (int row = gw; row < N; row += 1024) {
        unsigned long long key = best[row];
        int j = (int)(~(unsigned)(key & 0xffffffffull));
        float rni = rnorm[row], rnj = rnorm[j];
        const float* pi = in + (size_t)row * D;
        const float* pj = in + (size_t)j * D;
        float s = 0.f;
#pragma unroll
        for (int c = 0; c < 6; ++c) {
            float xi = pi[lane + 64 * c] * rni;
            float xj = pj[lane + 64 * c] * rnj;
            float dvv = xi - xj + EPS;               // ||x - nn_x + eps||
            s += dvv * dvv;
        }
#pragma unroll
        for (int off = 32; off > 0; off >>= 1) s += __shfl_down(s, off, 64);
        if (lane == 0) local += -logf(sqrtf(s) + EPS);
    }
    if (lane == 0) part[wave] = local;
    __syncthreads();
    if (threadIdx.x == 0)
        atomicAdd(out, (part[0] + part[1] + part[2] + part[3]) / (float)N);
}

extern "C" void kernel_launch(void* const* d_in, const int* in_sizes, int n_in,
                              void* d_out, int out_size, void* d_ws, size_t ws_size,
                              hipStream_t stream) {
    const float* in = (const float*)d_in[0];
    float* out = (float*)d_out;
    const int N = in_sizes[0] / D;                   // 8192

    // workspace layout: rnorm (N f32) | best (N u64) | xb (N*D bf16)
    char* ws = (char*)d_ws;
    float* rnorm = (float*)ws;
    unsigned long long* best = (unsigned long long*)(ws + 64 * 1024);
    __hip_bfloat16* xb = (__hip_bfloat16*)(ws + 192 * 1024);

    // best/out zeroing folded into prep_kernel (2 fewer graph nodes)
    prep_kernel<<<N / 4, 256, 0, stream>>>(in, rnorm, xb, best, out, N);
    maxdot_rows<<<512, 256, 0, stream>>>(xb, best);        // 32 row-blocks x 16 col-splits
    loss_kernel<<<256, 256, 0, stream>>>(in, rnorm, best, out, N);
}